// Round 3
// baseline (600.036 us; speedup 1.0000x reference)
//
#include <hip/hip_runtime.h>

#define N_NODES 50000
#define BN_EPS 1e-5f
#define SCAN_CHUNK 2048

typedef __attribute__((ext_vector_type(8))) short short8;
typedef __attribute__((ext_vector_type(4))) float f32x4;

__device__ __forceinline__ unsigned short f2b(float x) {
    unsigned int u = __float_as_uint(x);
    unsigned int r = (u + 0x7fffu + ((u >> 16) & 1u)) >> 16;
    return (unsigned short)r;
}
__device__ __forceinline__ float b2f_lo(unsigned int u) { return __uint_as_float(u << 16); }
__device__ __forceinline__ float b2f_hi(unsigned int u) { return __uint_as_float(u & 0xffff0000u); }
__device__ __forceinline__ unsigned int pack2(float lo, float hi) {
    return (unsigned int)f2b(lo) | ((unsigned int)f2b(hi) << 16);
}
__device__ __forceinline__ float us2f(unsigned short s) {
    return __uint_as_float(((unsigned int)s) << 16);
}

// ---------------- edge dtype detector ----------------
__global__ void k_detect64(const int* __restrict__ e, int* __restrict__ flag) {
    __shared__ int snz[256];
    int i = threadIdx.x;
    snz[i] = e[2 * i + 1];
    __syncthreads();
    if (i == 0) {
        int nz = 0;
        for (int j = 0; j < 256; ++j) nz |= snz[j];
        *flag = (nz == 0) ? 1 : 0;
    }
}

__device__ __forceinline__ int edge_at(const int* e32, const long long* e64, int is64, long long idx) {
    return is64 ? (int)e64[idx] : e32[idx];
}

// ---------------- CSR build ----------------
__global__ void k_deg_count(const int* __restrict__ e, const int* __restrict__ flag,
                            int* __restrict__ cnt, int E) {
    int is64 = *flag;
    const long long* e64 = (const long long*)e;
    int i = blockIdx.x * blockDim.x + threadIdx.x;
    int stride = gridDim.x * blockDim.x;
    for (; i < E; i += stride) {
        int d = edge_at(e, e64, is64, (long long)E + i);
        atomicAdd(&cnt[d], 1);
    }
}

__global__ void k_dinv(const int* __restrict__ cnt, float* __restrict__ dinv, int n) {
    int i = blockIdx.x * blockDim.x + threadIdx.x;
    if (i < n) dinv[i] = rsqrtf((float)(cnt[i] + 1));
}

__global__ void k_chunk_sum(const int* __restrict__ cnt, int* __restrict__ bsum, int n) {
    __shared__ int sb[256];
    int base = blockIdx.x * SCAN_CHUNK;
    int s = 0;
    for (int j = threadIdx.x; j < SCAN_CHUNK; j += 256) {
        int i = base + j;
        if (i < n) s += cnt[i];
    }
    sb[threadIdx.x] = s;
    __syncthreads();
    for (int off = 128; off > 0; off >>= 1) {
        if (threadIdx.x < off) sb[threadIdx.x] += sb[threadIdx.x + off];
        __syncthreads();
    }
    if (threadIdx.x == 0) bsum[blockIdx.x] = sb[0];
}

__global__ void k_scan_sums(const int* __restrict__ bsum, int* __restrict__ boff,
                            int* __restrict__ row_ptr, int nchunks, int n) {
    if (threadIdx.x == 0 && blockIdx.x == 0) {
        int run = 0;
        for (int b = 0; b < nchunks; ++b) { boff[b] = run; run += bsum[b]; }
        row_ptr[n] = run;
    }
}

__global__ void k_local_scan(const int* __restrict__ cnt, const int* __restrict__ boff,
                             int* __restrict__ row_ptr, int* __restrict__ cursor, int n) {
    __shared__ int sb[256];
    int tid = threadIdx.x;
    int base = blockIdx.x * SCAN_CHUNK + tid * 8;
    int v[8];
    int ts = 0;
#pragma unroll
    for (int j = 0; j < 8; ++j) {
        int i = base + j;
        v[j] = (i < n) ? cnt[i] : 0;
        ts += v[j];
    }
    sb[tid] = ts;
    __syncthreads();
    for (int off = 1; off < 256; off <<= 1) {
        int t = (tid >= off) ? sb[tid - off] : 0;
        __syncthreads();
        sb[tid] += t;
        __syncthreads();
    }
    int excl = sb[tid] - ts + boff[blockIdx.x];
#pragma unroll
    for (int j = 0; j < 8; ++j) {
        int i = base + j;
        if (i < n) { row_ptr[i] = excl; cursor[i] = excl; }
        excl += v[j];
    }
}

__global__ void k_fill(const int* __restrict__ e, const int* __restrict__ flag,
                       const float* __restrict__ dinv, int* __restrict__ cursor,
                       int2* __restrict__ ew, int E) {
    int is64 = *flag;
    const long long* e64 = (const long long*)e;
    int i = blockIdx.x * blockDim.x + threadIdx.x;
    int stride = gridDim.x * blockDim.x;
    for (; i < E; i += stride) {
        int s = edge_at(e, e64, is64, i);
        int d = edge_at(e, e64, is64, (long long)E + i);
        int pos = atomicAdd(&cursor[d], 1);
        ew[pos] = make_int2(s, __float_as_int(dinv[s] * dinv[d]));
    }
}

// ---------------- fp32 -> bf16 cast ----------------
__global__ void k_cast(const float* __restrict__ x, unsigned int* __restrict__ xb, int n32) {
    int i = blockIdx.x * blockDim.x + threadIdx.x;
    int stride = gridDim.x * blockDim.x;
    const float2* x2 = (const float2*)x;
    for (; i < n32; i += stride) {
        float2 v = x2[i];
        xb[i] = pack2(v.x, v.y);
    }
}

// ---------------- W prepack into MFMA B-fragment layout ----------------
__global__ void k_prepack(const float* __restrict__ W1, const float* __restrict__ W2,
                          const float* __restrict__ W3, const float* __restrict__ Wl,
                          unsigned short* __restrict__ bp) {
    int job = blockIdx.x;
    const float* src;
    int rowoff = 0;
    if (job == 0) src = W1;
    else if (job == 1) src = W2;
    else if (job == 2) src = W3;
    else { src = Wl; rowoff = (job - 3) * 128; }
    unsigned short* dst = bp + job * 16384;
    for (int idx = threadIdx.x; idx < 16384; idx += 256) {
        int j = idx & 7, l = (idx >> 3) & 63, kt = (idx >> 9) & 3, nt = idx >> 11;
        int row = kt * 32 + (l >> 4) * 8 + j;
        int col = nt * 16 + (l & 15);
        dst[idx] = f2b(src[(rowoff + row) * 128 + col]);
    }
}

// ---------------- layer GEMM: zb = A @ (sc .* W) + c, bf16 out ----------------
template <int HAS_AFF>
__global__ __launch_bounds__(256) void k_gemm_z(const unsigned short* __restrict__ A,
                                                const unsigned short* __restrict__ Bp,
                                                const float* __restrict__ sc,
                                                const float* __restrict__ cvec,
                                                unsigned short* __restrict__ zb, int n) {
    int tid = threadIdx.x;
    int l = tid & 63, w = tid >> 6;
    int kgrp = l >> 4, rit = l & 15;
    const short8* bp8 = (const short8*)Bp;
    short8 breg[8][4];
#pragma unroll
    for (int kt = 0; kt < 4; ++kt) {
        float sv[8];
        if (HAS_AFF) {
            float4 a = *(const float4*)&sc[kt * 32 + kgrp * 8];
            float4 b = *(const float4*)&sc[kt * 32 + kgrp * 8 + 4];
            sv[0] = a.x; sv[1] = a.y; sv[2] = a.z; sv[3] = a.w;
            sv[4] = b.x; sv[5] = b.y; sv[6] = b.z; sv[7] = b.w;
        }
#pragma unroll
        for (int nt = 0; nt < 8; ++nt) {
            short8 raw = bp8[(nt * 4 + kt) * 64 + l];
            if (HAS_AFF) {
                short8 r;
#pragma unroll
                for (int j = 0; j < 8; ++j)
                    r[j] = (short)f2b(us2f((unsigned short)raw[j]) * sv[j]);
                breg[nt][kt] = r;
            } else {
                breg[nt][kt] = raw;
            }
        }
    }
    int ntile = n >> 4;
    int nwav = gridDim.x * 4;
    for (int tile = blockIdx.x * 4 + w; tile < ntile; tile += nwav) {
        int r0 = tile * 16;
        const unsigned short* arow = A + (size_t)(r0 + rit) * 128 + kgrp * 8;
        f32x4 acc[8];
#pragma unroll
        for (int nt = 0; nt < 8; ++nt) acc[nt] = (f32x4)(0.f);
#pragma unroll
        for (int kt = 0; kt < 4; ++kt) {
            short8 af = *(const short8*)(arow + kt * 32);
#pragma unroll
            for (int nt = 0; nt < 8; ++nt)
                acc[nt] = __builtin_amdgcn_mfma_f32_16x16x32_bf16(af, breg[nt][kt], acc[nt], 0, 0, 0);
        }
        int crow0 = (l >> 4) * 4, ccol = l & 15;
#pragma unroll
        for (int nt = 0; nt < 8; ++nt) {
            int col = nt * 16 + ccol;
            float cv = HAS_AFF ? cvec[col] : 0.f;
#pragma unroll
            for (int j = 0; j < 4; ++j)
                zb[(size_t)(r0 + crow0 + j) * 128 + col] = f2b(acc[nt][j] + cv);
        }
    }
}

// ---------------- CSR-pull aggregate + relu + BN stats ----------------
__global__ __launch_bounds__(256) void k_agg(const unsigned short* __restrict__ zb,
                                             const int* __restrict__ row_ptr,
                                             const int2* __restrict__ ew,
                                             const float* __restrict__ dinv,
                                             const float* __restrict__ bias,
                                             unsigned int* __restrict__ tb,
                                             float* __restrict__ stats, int n) {
    int tid = threadIdx.x;
    int l = tid & 63, w = tid >> 6;
    float b0 = bias[2 * l], b1 = bias[2 * l + 1];
    float s0 = 0.f, s1 = 0.f, q0 = 0.f, q1 = 0.f;
    const unsigned int* z32 = (const unsigned int*)zb;
    for (int node = blockIdx.x * 4 + w; node < n; node += 8192) {
        float di = dinv[node];
        float di2 = di * di;
        unsigned int us = z32[(size_t)node * 64 + l];
        float acc0 = fmaf(di2, b2f_lo(us), b0);
        float acc1 = fmaf(di2, b2f_hi(us), b1);
        int e = row_ptr[node], e1 = row_ptr[node + 1];
        for (; e + 4 <= e1; e += 4) {
            int2 p0 = ew[e], p1 = ew[e + 1], p2 = ew[e + 2], p3 = ew[e + 3];
            unsigned int u0 = z32[(size_t)p0.x * 64 + l];
            unsigned int u1 = z32[(size_t)p1.x * 64 + l];
            unsigned int u2 = z32[(size_t)p2.x * 64 + l];
            unsigned int u3 = z32[(size_t)p3.x * 64 + l];
            float w0 = __int_as_float(p0.y), w1 = __int_as_float(p1.y);
            float w2 = __int_as_float(p2.y), w3 = __int_as_float(p3.y);
            acc0 = fmaf(w0, b2f_lo(u0), acc0); acc1 = fmaf(w0, b2f_hi(u0), acc1);
            acc0 = fmaf(w1, b2f_lo(u1), acc0); acc1 = fmaf(w1, b2f_hi(u1), acc1);
            acc0 = fmaf(w2, b2f_lo(u2), acc0); acc1 = fmaf(w2, b2f_hi(u2), acc1);
            acc0 = fmaf(w3, b2f_lo(u3), acc0); acc1 = fmaf(w3, b2f_hi(u3), acc1);
        }
        for (; e < e1; ++e) {
            int2 p = ew[e];
            unsigned int u = z32[(size_t)p.x * 64 + l];
            float wv = __int_as_float(p.y);
            acc0 = fmaf(wv, b2f_lo(u), acc0);
            acc1 = fmaf(wv, b2f_hi(u), acc1);
        }
        acc0 = fmaxf(acc0, 0.f);
        acc1 = fmaxf(acc1, 0.f);
        s0 += acc0; s1 += acc1;
        q0 = fmaf(acc0, acc0, q0); q1 = fmaf(acc1, acc1, q1);
        tb[(size_t)node * 64 + l] = pack2(acc0, acc1);
    }
    __shared__ float red[4][256];
    red[0][tid] = s0; red[1][tid] = s1; red[2][tid] = q0; red[3][tid] = q1;
    __syncthreads();
    int k = tid >> 6, li = tid & 63;
    float v = red[k][li] + red[k][64 + li] + red[k][128 + li] + red[k][192 + li];
    int f = 2 * li + (k & 1) + ((k >> 1) ? 128 : 0);
    atomicAdd(&stats[f], v);
}

__global__ void k_bn_finalize(const float* __restrict__ stats, const float* __restrict__ g,
                              const float* __restrict__ be, float* __restrict__ ss, float invn) {
    int f = threadIdx.x;
    float m = stats[f] * invn;
    float v = stats[128 + f] * invn - m * m;
    float sc = g[f] * rsqrtf(v + BN_EPS);
    ss[f] = sc;
    ss[128 + f] = fmaf(-m, sc, be[f]);
}

// c[col] = (init) + sum_k sh[k] * W[k][col].  MODE 0: c=dot; 1: c=base+dot; 2: c+=dot.
template <int MODE>
__global__ void k_shiftdot(const float* __restrict__ W, const float* __restrict__ ss,
                           const float* __restrict__ base, float* __restrict__ c) {
    int col = threadIdx.x;  // 128 threads
    float acc = (MODE == 1) ? base[col] : ((MODE == 2) ? c[col] : 0.f);
    const float* sh = ss + 128;
    for (int k = 0; k < 128; ++k) acc = fmaf(sh[k], W[k * 128 + col], acc);
    c[col] = acc;
}

// ---------------- final GEMM: out = relu(sum_b t_b @ (sc_b .* Wl_b) + cl), fp32 ----------------
__global__ __launch_bounds__(256) void k_gemm_final(const unsigned short* __restrict__ t1,
                                                    const unsigned short* __restrict__ t2,
                                                    const unsigned short* __restrict__ t3,
                                                    const unsigned short* __restrict__ Bp,
                                                    const float* __restrict__ ss1,
                                                    const float* __restrict__ ss2,
                                                    const float* __restrict__ ss3,
                                                    const float* __restrict__ cl,
                                                    float* __restrict__ out, int n) {
    int tid = threadIdx.x;
    int l = tid & 63, w = tid >> 6;
    int kgrp = l >> 4, rit = l & 15;
    const short8* bp8 = (const short8*)Bp;
    short8 breg[2][12];
    const float* sss[3] = {ss1, ss2, ss3};
#pragma unroll
    for (int b = 0; b < 3; ++b) {
        const float* sc = sss[b];
#pragma unroll
        for (int ktl = 0; ktl < 4; ++ktl) {
            float4 a = *(const float4*)&sc[ktl * 32 + kgrp * 8];
            float4 bb = *(const float4*)&sc[ktl * 32 + kgrp * 8 + 4];
            float sv[8] = {a.x, a.y, a.z, a.w, bb.x, bb.y, bb.z, bb.w};
#pragma unroll
            for (int i = 0; i < 2; ++i) {
                int nt = 2 * w + i;
                short8 raw = bp8[b * 2048 + (nt * 4 + ktl) * 64 + l];
                short8 r;
#pragma unroll
                for (int j = 0; j < 8; ++j)
                    r[j] = (short)f2b(us2f((unsigned short)raw[j]) * sv[j]);
                breg[i][b * 4 + ktl] = r;
            }
        }
    }
    int ntile = n >> 4;
    for (int tile = blockIdx.x; tile < ntile; tile += gridDim.x) {
        int r0 = tile * 16;
        f32x4 acc0 = (f32x4)(0.f), acc1 = (f32x4)(0.f);
        const unsigned short* tbs[3] = {t1, t2, t3};
#pragma unroll
        for (int b = 0; b < 3; ++b) {
            const unsigned short* arow = tbs[b] + (size_t)(r0 + rit) * 128 + kgrp * 8;
#pragma unroll
            for (int ktl = 0; ktl < 4; ++ktl) {
                short8 af = *(const short8*)(arow + ktl * 32);
                acc0 = __builtin_amdgcn_mfma_f32_16x16x32_bf16(af, breg[0][b * 4 + ktl], acc0, 0, 0, 0);
                acc1 = __builtin_amdgcn_mfma_f32_16x16x32_bf16(af, breg[1][b * 4 + ktl], acc1, 0, 0, 0);
            }
        }
        int crow0 = (l >> 4) * 4, ccol = l & 15;
        int col0 = (2 * w) * 16 + ccol, col1 = (2 * w + 1) * 16 + ccol;
        float cv0 = cl[col0], cv1 = cl[col1];
#pragma unroll
        for (int j = 0; j < 4; ++j) {
            int row = r0 + crow0 + j;
            out[(size_t)row * 128 + col0] = fmaxf(acc0[j] + cv0, 0.f);
            out[(size_t)row * 128 + col1] = fmaxf(acc1[j] + cv1, 0.f);
        }
    }
}

extern "C" void kernel_launch(void* const* d_in, const int* in_sizes, int n_in,
                              void* d_out, int out_size, void* d_ws, size_t ws_size,
                              hipStream_t stream) {
    const float* x   = (const float*)d_in[0];
    const int*   ei  = (const int*)d_in[1];
    const float* W1  = (const float*)d_in[3];
    const float* b1  = (const float*)d_in[4];
    const float* g1  = (const float*)d_in[5];
    const float* be1 = (const float*)d_in[6];
    const float* W2  = (const float*)d_in[7];
    const float* b2  = (const float*)d_in[8];
    const float* g2  = (const float*)d_in[9];
    const float* be2 = (const float*)d_in[10];
    const float* W3  = (const float*)d_in[11];
    const float* b3  = (const float*)d_in[12];
    const float* g3  = (const float*)d_in[13];
    const float* be3 = (const float*)d_in[14];
    const float* Wl  = (const float*)d_in[15];
    const float* bl  = (const float*)d_in[16];
    float* out = (float*)d_out;

    const int n = N_NODES;
    const int E = in_sizes[1] / 2;

    char* ws = (char*)d_ws;
    size_t off = 0;
    auto alloc = [&](size_t bytes) -> void* {
        void* p = ws + off;
        off += (bytes + 255) & ~((size_t)255);
        return p;
    };
    float*          dinv    = (float*)alloc((size_t)n * 4);
    int*            cnt     = (int*)alloc((size_t)n * 4);
    int*            row_ptr = (int*)alloc((size_t)(n + 1) * 4);
    int*            cursor  = (int*)alloc((size_t)n * 4);
    int*            bsum    = (int*)alloc(64 * 4);
    int*            boff    = (int*)alloc(64 * 4);
    float*          stats   = (float*)alloc(256 * 4);
    float*          ss1     = (float*)alloc(256 * 4);
    float*          ss2     = (float*)alloc(256 * 4);
    float*          ss3     = (float*)alloc(256 * 4);
    float*          c2      = (float*)alloc(128 * 4);
    float*          c3      = (float*)alloc(128 * 4);
    float*          cl      = (float*)alloc(128 * 4);
    int*            flag    = (int*)alloc(256);
    int2*           ew      = (int2*)alloc((size_t)E * 8);
    unsigned short* bp      = (unsigned short*)alloc(6 * 16384 * 2);
    unsigned int*   xb      = (unsigned int*)alloc((size_t)n * 64 * 4);
    unsigned short* zb      = (unsigned short*)alloc((size_t)n * 128 * 2);
    unsigned int*   tb1     = (unsigned int*)alloc((size_t)n * 64 * 4);
    unsigned int*   tb2     = (unsigned int*)alloc((size_t)n * 64 * 4);
    unsigned int*   tb3     = (unsigned int*)alloc((size_t)n * 64 * 4);

    // ---- CSR build ----
    hipMemsetAsync(cnt, 0, (size_t)n * 4, stream);
    k_detect64<<<1, 256, 0, stream>>>(ei, flag);
    k_deg_count<<<512, 256, 0, stream>>>(ei, flag, cnt, E);
    k_dinv<<<(n + 255) / 256, 256, 0, stream>>>(cnt, dinv, n);
    int nchunks = (n + SCAN_CHUNK - 1) / SCAN_CHUNK;
    k_chunk_sum<<<nchunks, 256, 0, stream>>>(cnt, bsum, n);
    k_scan_sums<<<1, 32, 0, stream>>>(bsum, boff, row_ptr, nchunks, n);
    k_local_scan<<<nchunks, 256, 0, stream>>>(cnt, boff, row_ptr, cursor, n);
    k_fill<<<512, 256, 0, stream>>>(ei, flag, dinv, cursor, ew, E);

    // ---- precompute ----
    k_cast<<<2048, 256, 0, stream>>>(x, xb, n * 64);
    k_prepack<<<6, 256, 0, stream>>>(W1, W2, W3, Wl, bp);

    const unsigned short* t1u = (const unsigned short*)tb1;
    const unsigned short* t2u = (const unsigned short*)tb2;
    const unsigned short* t3u = (const unsigned short*)tb3;

    // ---- layer 1 ----
    k_gemm_z<0><<<512, 256, 0, stream>>>((const unsigned short*)xb, bp, nullptr, nullptr, zb, n);
    hipMemsetAsync(stats, 0, 256 * 4, stream);
    k_agg<<<2048, 256, 0, stream>>>(zb, row_ptr, ew, dinv, b1, tb1, stats, n);
    k_bn_finalize<<<1, 128, 0, stream>>>(stats, g1, be1, ss1, 1.0f / n);
    k_shiftdot<0><<<1, 128, 0, stream>>>(W2, ss1, nullptr, c2);
    k_shiftdot<1><<<1, 128, 0, stream>>>(Wl, ss1, bl, cl);

    // ---- layer 2 ----
    k_gemm_z<1><<<512, 256, 0, stream>>>(t1u, bp + 16384, ss1, c2, zb, n);
    hipMemsetAsync(stats, 0, 256 * 4, stream);
    k_agg<<<2048, 256, 0, stream>>>(zb, row_ptr, ew, dinv, b2, tb2, stats, n);
    k_bn_finalize<<<1, 128, 0, stream>>>(stats, g2, be2, ss2, 1.0f / n);
    k_shiftdot<0><<<1, 128, 0, stream>>>(W3, ss2, nullptr, c3);
    k_shiftdot<2><<<1, 128, 0, stream>>>(Wl + 128 * 128, ss2, nullptr, cl);

    // ---- layer 3 ----
    k_gemm_z<1><<<512, 256, 0, stream>>>(t2u, bp + 2 * 16384, ss2, c3, zb, n);
    hipMemsetAsync(stats, 0, 256 * 4, stream);
    k_agg<<<2048, 256, 0, stream>>>(zb, row_ptr, ew, dinv, b3, tb3, stats, n);
    k_bn_finalize<<<1, 128, 0, stream>>>(stats, g3, be3, ss3, 1.0f / n);
    k_shiftdot<2><<<1, 128, 0, stream>>>(Wl + 2 * 128 * 128, ss3, nullptr, cl);

    // ---- final fused GEMM over K=384 ----
    k_gemm_final<<<512, 256, 0, stream>>>(t1u, t2u, t3u, bp + 3 * 16384,
                                          ss1, ss2, ss3, cl, out, n);
}

// Round 4
// 354.564 us; speedup vs baseline: 1.6923x; 1.6923x over previous
//
#include <hip/hip_runtime.h>

#define N_NODES 50000
#define BN_EPS 1e-5f
#define SCAN_CHUNK 2048

typedef __attribute__((ext_vector_type(8))) short short8;
typedef __attribute__((ext_vector_type(4))) float f32x4;

__device__ __forceinline__ unsigned short f2b(float x) {
    unsigned int u = __float_as_uint(x);
    unsigned int r = (u + 0x7fffu + ((u >> 16) & 1u)) >> 16;
    return (unsigned short)r;
}
__device__ __forceinline__ float b2f_lo(unsigned int u) { return __uint_as_float(u << 16); }
__device__ __forceinline__ float b2f_hi(unsigned int u) { return __uint_as_float(u & 0xffff0000u); }
__device__ __forceinline__ unsigned int pack2(float lo, float hi) {
    return (unsigned int)f2b(lo) | ((unsigned int)f2b(hi) << 16);
}
__device__ __forceinline__ float us2f(unsigned short s) {
    return __uint_as_float(((unsigned int)s) << 16);
}

// ---------------- edge dtype detector ----------------
__global__ void k_detect64(const int* __restrict__ e, int* __restrict__ flag) {
    __shared__ int snz[256];
    int i = threadIdx.x;
    snz[i] = e[2 * i + 1];
    __syncthreads();
    if (i == 0) {
        int nz = 0;
        for (int j = 0; j < 256; ++j) nz |= snz[j];
        *flag = (nz == 0) ? 1 : 0;
    }
}

__device__ __forceinline__ int edge_at(const int* e32, const long long* e64, int is64, long long idx) {
    return is64 ? (int)e64[idx] : e32[idx];
}

// ---------------- CSR build ----------------
__global__ void k_deg_count(const int* __restrict__ e, const int* __restrict__ flag,
                            int* __restrict__ cnt, int E) {
    int is64 = *flag;
    const long long* e64 = (const long long*)e;
    int i = blockIdx.x * blockDim.x + threadIdx.x;
    int stride = gridDim.x * blockDim.x;
    for (; i < E; i += stride) {
        int d = edge_at(e, e64, is64, (long long)E + i);
        atomicAdd(&cnt[d], 1);
    }
}

__global__ void k_dinv(const int* __restrict__ cnt, float* __restrict__ dinv, int n) {
    int i = blockIdx.x * blockDim.x + threadIdx.x;
    if (i < n) dinv[i] = rsqrtf((float)(cnt[i] + 1));
}

__global__ void k_chunk_sum(const int* __restrict__ cnt, int* __restrict__ bsum, int n) {
    __shared__ int sb[256];
    int base = blockIdx.x * SCAN_CHUNK;
    int s = 0;
    for (int j = threadIdx.x; j < SCAN_CHUNK; j += 256) {
        int i = base + j;
        if (i < n) s += cnt[i];
    }
    sb[threadIdx.x] = s;
    __syncthreads();
    for (int off = 128; off > 0; off >>= 1) {
        if (threadIdx.x < off) sb[threadIdx.x] += sb[threadIdx.x + off];
        __syncthreads();
    }
    if (threadIdx.x == 0) bsum[blockIdx.x] = sb[0];
}

__global__ void k_scan_sums(const int* __restrict__ bsum, int* __restrict__ boff,
                            int* __restrict__ row_ptr, int nchunks, int n) {
    if (threadIdx.x == 0 && blockIdx.x == 0) {
        int run = 0;
        for (int b = 0; b < nchunks; ++b) { boff[b] = run; run += bsum[b]; }
        row_ptr[n] = run;
    }
}

__global__ void k_local_scan(const int* __restrict__ cnt, const int* __restrict__ boff,
                             int* __restrict__ row_ptr, int* __restrict__ cursor, int n) {
    __shared__ int sb[256];
    int tid = threadIdx.x;
    int base = blockIdx.x * SCAN_CHUNK + tid * 8;
    int v[8];
    int ts = 0;
#pragma unroll
    for (int j = 0; j < 8; ++j) {
        int i = base + j;
        v[j] = (i < n) ? cnt[i] : 0;
        ts += v[j];
    }
    sb[tid] = ts;
    __syncthreads();
    for (int off = 1; off < 256; off <<= 1) {
        int t = (tid >= off) ? sb[tid - off] : 0;
        __syncthreads();
        sb[tid] += t;
        __syncthreads();
    }
    int excl = sb[tid] - ts + boff[blockIdx.x];
#pragma unroll
    for (int j = 0; j < 8; ++j) {
        int i = base + j;
        if (i < n) { row_ptr[i] = excl; cursor[i] = excl; }
        excl += v[j];
    }
}

__global__ void k_fill(const int* __restrict__ e, const int* __restrict__ flag,
                       const float* __restrict__ dinv, int* __restrict__ cursor,
                       int2* __restrict__ ew, int E) {
    int is64 = *flag;
    const long long* e64 = (const long long*)e;
    int i = blockIdx.x * blockDim.x + threadIdx.x;
    int stride = gridDim.x * blockDim.x;
    for (; i < E; i += stride) {
        int s = edge_at(e, e64, is64, i);
        int d = edge_at(e, e64, is64, (long long)E + i);
        int pos = atomicAdd(&cursor[d], 1);
        ew[pos] = make_int2(s, __float_as_int(dinv[s] * dinv[d]));
    }
}

// ---------------- W prepack into MFMA B-fragment layout ----------------
__global__ void k_prepack(const float* __restrict__ W1, const float* __restrict__ W2,
                          const float* __restrict__ W3, const float* __restrict__ Wl,
                          unsigned short* __restrict__ bp) {
    int job = blockIdx.x;
    const float* src;
    int rowoff = 0;
    if (job == 0) src = W1;
    else if (job == 1) src = W2;
    else if (job == 2) src = W3;
    else { src = Wl; rowoff = (job - 3) * 128; }
    unsigned short* dst = bp + job * 16384;
    for (int idx = threadIdx.x; idx < 16384; idx += 256) {
        int j = idx & 7, l = (idx >> 3) & 63, kt = (idx >> 9) & 3, nt = idx >> 11;
        int row = kt * 32 + (l >> 4) * 8 + j;
        int col = nt * 16 + (l & 15);
        dst[idx] = f2b(src[(rowoff + row) * 128 + col]);
    }
}

// ---------------- layer GEMM: zb = A @ (sc .* W) + c, bf16 out ----------------
// A32: A is fp32 (layer 1 reads x directly, no cast pass).
template <int HAS_AFF, int A32>
__global__ __launch_bounds__(256) void k_gemm_z(const void* __restrict__ Av,
                                                const unsigned short* __restrict__ Bp,
                                                const float* __restrict__ sc,
                                                const float* __restrict__ cvec,
                                                unsigned short* __restrict__ zb, int n) {
    int tid = threadIdx.x;
    int l = tid & 63, w = tid >> 6;
    int kgrp = l >> 4, rit = l & 15;
    const short8* bp8 = (const short8*)Bp;
    short8 breg[8][4];
#pragma unroll
    for (int kt = 0; kt < 4; ++kt) {
        float sv[8];
        if (HAS_AFF) {
            float4 a = *(const float4*)&sc[kt * 32 + kgrp * 8];
            float4 b = *(const float4*)&sc[kt * 32 + kgrp * 8 + 4];
            sv[0] = a.x; sv[1] = a.y; sv[2] = a.z; sv[3] = a.w;
            sv[4] = b.x; sv[5] = b.y; sv[6] = b.z; sv[7] = b.w;
        }
#pragma unroll
        for (int nt = 0; nt < 8; ++nt) {
            short8 raw = bp8[(nt * 4 + kt) * 64 + l];
            if (HAS_AFF) {
                short8 r;
#pragma unroll
                for (int j = 0; j < 8; ++j)
                    r[j] = (short)f2b(us2f((unsigned short)raw[j]) * sv[j]);
                breg[nt][kt] = r;
            } else {
                breg[nt][kt] = raw;
            }
        }
    }
    int ntile = n >> 4;
    int nwav = gridDim.x * 4;
    for (int tile = blockIdx.x * 4 + w; tile < ntile; tile += nwav) {
        int r0 = tile * 16;
        f32x4 acc[8];
#pragma unroll
        for (int nt = 0; nt < 8; ++nt) acc[nt] = (f32x4)(0.f);
#pragma unroll
        for (int kt = 0; kt < 4; ++kt) {
            short8 af;
            if (A32) {
                const float* a32 = (const float*)Av + (size_t)(r0 + rit) * 128 + kgrp * 8 + kt * 32;
                float4 fa = *(const float4*)a32;
                float4 fb = *(const float4*)(a32 + 4);
                af[0] = (short)f2b(fa.x); af[1] = (short)f2b(fa.y);
                af[2] = (short)f2b(fa.z); af[3] = (short)f2b(fa.w);
                af[4] = (short)f2b(fb.x); af[5] = (short)f2b(fb.y);
                af[6] = (short)f2b(fb.z); af[7] = (short)f2b(fb.w);
            } else {
                const unsigned short* a16 = (const unsigned short*)Av + (size_t)(r0 + rit) * 128 + kgrp * 8 + kt * 32;
                af = *(const short8*)a16;
            }
#pragma unroll
            for (int nt = 0; nt < 8; ++nt)
                acc[nt] = __builtin_amdgcn_mfma_f32_16x16x32_bf16(af, breg[nt][kt], acc[nt], 0, 0, 0);
        }
        int crow0 = (l >> 4) * 4, ccol = l & 15;
#pragma unroll
        for (int nt = 0; nt < 8; ++nt) {
            int col = nt * 16 + ccol;
            float cv = HAS_AFF ? cvec[col] : 0.f;
#pragma unroll
            for (int j = 0; j < 4; ++j)
                zb[(size_t)(r0 + crow0 + j) * 128 + col] = f2b(acc[nt][j] + cv);
        }
    }
}

// ---------------- CSR-pull aggregate + relu + BN stats (one node per wave) ----------------
// 8-deep gather MLP with register double-buffered edge prefetch; branch-free tail via
// clamped index + zero weight. Stats striped 64-way to avoid same-address atomic storm.
__global__ __launch_bounds__(256) void k_agg(const unsigned short* __restrict__ zb,
                                             const int* __restrict__ row_ptr,
                                             const int2* __restrict__ ew,
                                             const float* __restrict__ dinv,
                                             const float* __restrict__ bias,
                                             unsigned int* __restrict__ tb,
                                             float* __restrict__ stats64, int n) {
    int tid = threadIdx.x;
    int l = tid & 63, w = tid >> 6;
    int node = blockIdx.x * 4 + w;  // grid is exactly n/4 blocks
    const unsigned int* z32 = (const unsigned int*)zb;
    float b0 = bias[2 * l], b1 = bias[2 * l + 1];
    float di = dinv[node];
    unsigned int us = z32[((size_t)node << 6) | l];
    float di2 = di * di;
    float acc0 = fmaf(di2, b2f_lo(us), b0);
    float acc1 = fmaf(di2, b2f_hi(us), b1);
    int e0 = row_ptr[node], e1 = row_ptr[node + 1];
    int last = max(e1 - 1, 0);
    int2 q[8];
#pragma unroll
    for (int j = 0; j < 8; ++j) {
        int idx = e0 + j;
        int2 t = ew[min(idx, last)];
        q[j] = make_int2(t.x, idx < e1 ? t.y : 0);
    }
    int iters = (e1 - e0 + 7) >> 3;
    for (int it = 0; it < iters; ++it) {
        unsigned int u[8];
        float wf[8];
#pragma unroll
        for (int j = 0; j < 8; ++j) {
            u[j] = z32[(size_t)(unsigned int)((q[j].x << 6) | l)];
            wf[j] = __int_as_float(q[j].y);
        }
        int eb = e0 + (it + 1) * 8;
#pragma unroll
        for (int j = 0; j < 8; ++j) {
            int idx = eb + j;
            int2 t = ew[min(idx, last)];
            q[j] = make_int2(t.x, idx < e1 ? t.y : 0);
        }
#pragma unroll
        for (int j = 0; j < 8; ++j) {
            acc0 = fmaf(wf[j], b2f_lo(u[j]), acc0);
            acc1 = fmaf(wf[j], b2f_hi(u[j]), acc1);
        }
    }
    acc0 = fmaxf(acc0, 0.f);
    acc1 = fmaxf(acc1, 0.f);
    tb[((size_t)node << 6) | l] = pack2(acc0, acc1);
    __shared__ float red[4][256];
    red[0][tid] = acc0; red[1][tid] = acc1;
    red[2][tid] = acc0 * acc0; red[3][tid] = acc1 * acc1;
    __syncthreads();
    int k = tid >> 6, li = tid & 63;
    float v = red[k][li] + red[k][64 + li] + red[k][128 + li] + red[k][192 + li];
    int f = 2 * li + (k & 1) + ((k >> 1) ? 128 : 0);
    atomicAdd(&stats64[(blockIdx.x & 63) * 256 + f], v);
}

// ---------------- fused BN finalize + shift-dot(s) ----------------
// MODE 0 (grid 2): blk0 -> ss + cn = sh@Wn ; blk1 -> cl = base + sh@Wl
// MODE 1 (grid 2): blk0 -> ss + cn = sh@Wn ; blk1 -> cl += sh@Wl
// MODE 2 (grid 1): blk0 -> ss ; cl += sh@Wl
template <int MODE>
__global__ void k_bn_findots(const float* __restrict__ stats64,
                             const float* __restrict__ g, const float* __restrict__ be,
                             float invn, float* __restrict__ ss_out,
                             const float* __restrict__ Wn, float* __restrict__ cn,
                             const float* __restrict__ Wl, const float* __restrict__ base,
                             float* __restrict__ cl) {
    int tid = threadIdx.x;  // 256
    float a = 0.f;
#pragma unroll 8
    for (int c = 0; c < 64; ++c) a += stats64[c * 256 + tid];
    __shared__ float sums[256];
    __shared__ float sh[128];
    __shared__ float scs[128];
    sums[tid] = a;
    __syncthreads();
    if (tid < 128) {
        float m = sums[tid] * invn;
        float var = sums[128 + tid] * invn - m * m;
        float sc = g[tid] * rsqrtf(var + BN_EPS);
        float shv = fmaf(-m, sc, be[tid]);
        sh[tid] = shv;
        scs[tid] = sc;
    }
    __syncthreads();
    if (blockIdx.x == 0 && tid < 128) {
        ss_out[tid] = scs[tid];
        ss_out[128 + tid] = sh[tid];
    }
    bool doCl = (MODE == 2) || (blockIdx.x == 1);
    const float* W = doCl ? Wl : Wn;
    int col = tid & 127, half = tid >> 7;
    float acc = 0.f;
#pragma unroll 4
    for (int k = half * 64; k < half * 64 + 64; ++k) acc = fmaf(sh[k], W[k * 128 + col], acc);
    __syncthreads();
    sums[tid] = acc;
    __syncthreads();
    if (tid < 128) {
        float tot = sums[tid] + sums[128 + tid];
        if (doCl) {
            float init = (MODE == 0) ? base[tid] : cl[tid];
            cl[tid] = init + tot;
        } else {
            cn[tid] = tot;
        }
    }
}

// ---------------- final GEMM: out = relu(sum_b t_b @ (sc_b .* Wl_b) + cl), fp32 ----------------
__global__ __launch_bounds__(256) void k_gemm_final(const unsigned short* __restrict__ t1,
                                                    const unsigned short* __restrict__ t2,
                                                    const unsigned short* __restrict__ t3,
                                                    const unsigned short* __restrict__ Bp,
                                                    const float* __restrict__ ss1,
                                                    const float* __restrict__ ss2,
                                                    const float* __restrict__ ss3,
                                                    const float* __restrict__ cl,
                                                    float* __restrict__ out, int n) {
    int tid = threadIdx.x;
    int l = tid & 63, w = tid >> 6;
    int kgrp = l >> 4, rit = l & 15;
    const short8* bp8 = (const short8*)Bp;
    short8 breg[2][12];
    const float* sss[3] = {ss1, ss2, ss3};
#pragma unroll
    for (int b = 0; b < 3; ++b) {
        const float* sc = sss[b];
#pragma unroll
        for (int ktl = 0; ktl < 4; ++ktl) {
            float4 a = *(const float4*)&sc[ktl * 32 + kgrp * 8];
            float4 bb = *(const float4*)&sc[ktl * 32 + kgrp * 8 + 4];
            float sv[8] = {a.x, a.y, a.z, a.w, bb.x, bb.y, bb.z, bb.w};
#pragma unroll
            for (int i = 0; i < 2; ++i) {
                int nt = 2 * w + i;
                short8 raw = bp8[b * 2048 + (nt * 4 + ktl) * 64 + l];
                short8 r;
#pragma unroll
                for (int j = 0; j < 8; ++j)
                    r[j] = (short)f2b(us2f((unsigned short)raw[j]) * sv[j]);
                breg[i][b * 4 + ktl] = r;
            }
        }
    }
    int ntile = n >> 4;
    for (int tile = blockIdx.x; tile < ntile; tile += gridDim.x) {
        int r0 = tile * 16;
        f32x4 acc0 = (f32x4)(0.f), acc1 = (f32x4)(0.f);
        const unsigned short* tbs[3] = {t1, t2, t3};
#pragma unroll
        for (int b = 0; b < 3; ++b) {
            const unsigned short* arow = tbs[b] + (size_t)(r0 + rit) * 128 + kgrp * 8;
#pragma unroll
            for (int ktl = 0; ktl < 4; ++ktl) {
                short8 af = *(const short8*)(arow + ktl * 32);
                acc0 = __builtin_amdgcn_mfma_f32_16x16x32_bf16(af, breg[0][b * 4 + ktl], acc0, 0, 0, 0);
                acc1 = __builtin_amdgcn_mfma_f32_16x16x32_bf16(af, breg[1][b * 4 + ktl], acc1, 0, 0, 0);
            }
        }
        int crow0 = (l >> 4) * 4, ccol = l & 15;
        int col0 = (2 * w) * 16 + ccol, col1 = (2 * w + 1) * 16 + ccol;
        float cv0 = cl[col0], cv1 = cl[col1];
#pragma unroll
        for (int j = 0; j < 4; ++j) {
            int row = r0 + crow0 + j;
            out[(size_t)row * 128 + col0] = fmaxf(acc0[j] + cv0, 0.f);
            out[(size_t)row * 128 + col1] = fmaxf(acc1[j] + cv1, 0.f);
        }
    }
}

extern "C" void kernel_launch(void* const* d_in, const int* in_sizes, int n_in,
                              void* d_out, int out_size, void* d_ws, size_t ws_size,
                              hipStream_t stream) {
    const float* x   = (const float*)d_in[0];
    const int*   ei  = (const int*)d_in[1];
    const float* W1  = (const float*)d_in[3];
    const float* b1  = (const float*)d_in[4];
    const float* g1  = (const float*)d_in[5];
    const float* be1 = (const float*)d_in[6];
    const float* W2  = (const float*)d_in[7];
    const float* b2  = (const float*)d_in[8];
    const float* g2  = (const float*)d_in[9];
    const float* be2 = (const float*)d_in[10];
    const float* W3  = (const float*)d_in[11];
    const float* b3  = (const float*)d_in[12];
    const float* g3  = (const float*)d_in[13];
    const float* be3 = (const float*)d_in[14];
    const float* Wl  = (const float*)d_in[15];
    const float* bl  = (const float*)d_in[16];
    float* out = (float*)d_out;

    const int n = N_NODES;
    const int E = in_sizes[1] / 2;

    char* ws = (char*)d_ws;
    size_t off = 0;
    auto alloc = [&](size_t bytes) -> void* {
        void* p = ws + off;
        off += (bytes + 255) & ~((size_t)255);
        return p;
    };
    // zero-region: cnt + 3 striped stats buffers, contiguous, one memset
    int*            cnt     = (int*)alloc((size_t)n * 4);
    float*          st1     = (float*)alloc(64 * 256 * 4);
    float*          st2     = (float*)alloc(64 * 256 * 4);
    float*          st3     = (float*)alloc(64 * 256 * 4);
    size_t zero_bytes = (size_t)((char*)st3 + 64 * 256 * 4 - (char*)cnt);

    float*          dinv    = (float*)alloc((size_t)n * 4);
    int*            row_ptr = (int*)alloc((size_t)(n + 1) * 4);
    int*            cursor  = (int*)alloc((size_t)n * 4);
    int*            bsum    = (int*)alloc(64 * 4);
    int*            boff    = (int*)alloc(64 * 4);
    float*          ss1     = (float*)alloc(256 * 4);
    float*          ss2     = (float*)alloc(256 * 4);
    float*          ss3     = (float*)alloc(256 * 4);
    float*          c2      = (float*)alloc(128 * 4);
    float*          c3      = (float*)alloc(128 * 4);
    float*          cl      = (float*)alloc(128 * 4);
    int*            flag    = (int*)alloc(256);
    int2*           ew      = (int2*)alloc((size_t)E * 8);
    unsigned short* bp      = (unsigned short*)alloc(6 * 16384 * 2);
    unsigned short* zb      = (unsigned short*)alloc((size_t)n * 128 * 2);
    unsigned int*   tb1     = (unsigned int*)alloc((size_t)n * 64 * 4);
    unsigned int*   tb2     = (unsigned int*)alloc((size_t)n * 64 * 4);
    unsigned int*   tb3     = (unsigned int*)alloc((size_t)n * 64 * 4);

    hipMemsetAsync(cnt, 0, zero_bytes, stream);

    // ---- CSR build ----
    k_detect64<<<1, 256, 0, stream>>>(ei, flag);
    k_deg_count<<<512, 256, 0, stream>>>(ei, flag, cnt, E);
    k_dinv<<<(n + 255) / 256, 256, 0, stream>>>(cnt, dinv, n);
    int nchunks = (n + SCAN_CHUNK - 1) / SCAN_CHUNK;
    k_chunk_sum<<<nchunks, 256, 0, stream>>>(cnt, bsum, n);
    k_scan_sums<<<1, 32, 0, stream>>>(bsum, boff, row_ptr, nchunks, n);
    k_local_scan<<<nchunks, 256, 0, stream>>>(cnt, boff, row_ptr, cursor, n);
    k_fill<<<512, 256, 0, stream>>>(ei, flag, dinv, cursor, ew, E);

    k_prepack<<<6, 256, 0, stream>>>(W1, W2, W3, Wl, bp);

    const unsigned short* t1u = (const unsigned short*)tb1;
    const unsigned short* t2u = (const unsigned short*)tb2;
    const unsigned short* t3u = (const unsigned short*)tb3;
    float invn = 1.0f / n;
    int aggblk = n / 4;  // one node per wave

    // ---- layer 1 (reads x fp32 directly) ----
    k_gemm_z<0, 1><<<782, 256, 0, stream>>>(x, bp, nullptr, nullptr, zb, n);
    k_agg<<<aggblk, 256, 0, stream>>>(zb, row_ptr, ew, dinv, b1, tb1, st1, n);
    k_bn_findots<0><<<2, 256, 0, stream>>>(st1, g1, be1, invn, ss1, W2, c2, Wl, bl, cl);

    // ---- layer 2 ----
    k_gemm_z<1, 0><<<782, 256, 0, stream>>>(t1u, bp + 16384, ss1, c2, zb, n);
    k_agg<<<aggblk, 256, 0, stream>>>(zb, row_ptr, ew, dinv, b2, tb2, st2, n);
    k_bn_findots<1><<<2, 256, 0, stream>>>(st2, g2, be2, invn, ss2, W3, c3, Wl + 16384, nullptr, cl);

    // ---- layer 3 ----
    k_gemm_z<1, 0><<<782, 256, 0, stream>>>(t2u, bp + 2 * 16384, ss2, c3, zb, n);
    k_agg<<<aggblk, 256, 0, stream>>>(zb, row_ptr, ew, dinv, b3, tb3, st3, n);
    k_bn_findots<2><<<1, 256, 0, stream>>>(st3, g3, be3, invn, ss3, nullptr, nullptr,
                                           Wl + 2 * 16384, nullptr, cl);

    // ---- final fused GEMM over K=384 ----
    k_gemm_final<<<512, 256, 0, stream>>>(t1u, t2u, t3u, bp + 3 * 16384,
                                          ss1, ss2, ss3, cl, out, n);
}

// Round 5
// 337.251 us; speedup vs baseline: 1.7792x; 1.0513x over previous
//
#include <hip/hip_runtime.h>

#define N_NODES 50000
#define BN_EPS 1e-5f
#define SCAN_CHUNK 2048

typedef __attribute__((ext_vector_type(8))) short short8;
typedef __attribute__((ext_vector_type(4))) float f32x4;

__device__ __forceinline__ unsigned short f2b(float x) {
    unsigned int u = __float_as_uint(x);
    unsigned int r = (u + 0x7fffu + ((u >> 16) & 1u)) >> 16;
    return (unsigned short)r;
}
__device__ __forceinline__ float b2f_lo(unsigned int u) { return __uint_as_float(u << 16); }
__device__ __forceinline__ float b2f_hi(unsigned int u) { return __uint_as_float(u & 0xffff0000u); }
__device__ __forceinline__ unsigned int pack2(float lo, float hi) {
    return (unsigned int)f2b(lo) | ((unsigned int)f2b(hi) << 16);
}
__device__ __forceinline__ float us2f(unsigned short s) {
    return __uint_as_float(((unsigned int)s) << 16);
}

// ---------------- edge dtype detector ----------------
__global__ void k_detect64(const int* __restrict__ e, int* __restrict__ flag) {
    __shared__ int snz[256];
    int i = threadIdx.x;
    snz[i] = e[2 * i + 1];
    __syncthreads();
    if (i == 0) {
        int nz = 0;
        for (int j = 0; j < 256; ++j) nz |= snz[j];
        *flag = (nz == 0) ? 1 : 0;
    }
}

__device__ __forceinline__ int edge_at(const int* e32, const long long* e64, int is64, long long idx) {
    return is64 ? (int)e64[idx] : e32[idx];
}

// ---------------- CSR build ----------------
__global__ void k_deg_count(const int* __restrict__ e, const int* __restrict__ flag,
                            int* __restrict__ cnt, int E) {
    int is64 = *flag;
    const long long* e64 = (const long long*)e;
    int i = blockIdx.x * blockDim.x + threadIdx.x;
    int stride = gridDim.x * blockDim.x;
    for (; i < E; i += stride) {
        int d = edge_at(e, e64, is64, (long long)E + i);
        atomicAdd(&cnt[d], 1);
    }
}

__global__ void k_dinv(const int* __restrict__ cnt, float* __restrict__ dinv, int n) {
    int i = blockIdx.x * blockDim.x + threadIdx.x;
    if (i < n) dinv[i] = rsqrtf((float)(cnt[i] + 1));
}

__global__ void k_chunk_sum(const int* __restrict__ cnt, int* __restrict__ bsum, int n) {
    __shared__ int sb[256];
    int base = blockIdx.x * SCAN_CHUNK;
    int s = 0;
    for (int j = threadIdx.x; j < SCAN_CHUNK; j += 256) {
        int i = base + j;
        if (i < n) s += cnt[i];
    }
    sb[threadIdx.x] = s;
    __syncthreads();
    for (int off = 128; off > 0; off >>= 1) {
        if (threadIdx.x < off) sb[threadIdx.x] += sb[threadIdx.x + off];
        __syncthreads();
    }
    if (threadIdx.x == 0) bsum[blockIdx.x] = sb[0];
}

__global__ void k_scan_sums(const int* __restrict__ bsum, int* __restrict__ boff,
                            int* __restrict__ row_ptr, int nchunks, int n) {
    if (threadIdx.x == 0 && blockIdx.x == 0) {
        int run = 0;
        for (int b = 0; b < nchunks; ++b) { boff[b] = run; run += bsum[b]; }
        row_ptr[n] = run;
    }
}

__global__ void k_local_scan(const int* __restrict__ cnt, const int* __restrict__ boff,
                             int* __restrict__ row_ptr, int* __restrict__ cursor, int n) {
    __shared__ int sb[256];
    int tid = threadIdx.x;
    int base = blockIdx.x * SCAN_CHUNK + tid * 8;
    int v[8];
    int ts = 0;
#pragma unroll
    for (int j = 0; j < 8; ++j) {
        int i = base + j;
        v[j] = (i < n) ? cnt[i] : 0;
        ts += v[j];
    }
    sb[tid] = ts;
    __syncthreads();
    for (int off = 1; off < 256; off <<= 1) {
        int t = (tid >= off) ? sb[tid - off] : 0;
        __syncthreads();
        sb[tid] += t;
        __syncthreads();
    }
    int excl = sb[tid] - ts + boff[blockIdx.x];
#pragma unroll
    for (int j = 0; j < 8; ++j) {
        int i = base + j;
        if (i < n) { row_ptr[i] = excl; cursor[i] = excl; }
        excl += v[j];
    }
}

__global__ void k_fill(const int* __restrict__ e, const int* __restrict__ flag,
                       const float* __restrict__ dinv, int* __restrict__ cursor,
                       int2* __restrict__ ew, int E) {
    int is64 = *flag;
    const long long* e64 = (const long long*)e;
    int i = blockIdx.x * blockDim.x + threadIdx.x;
    int stride = gridDim.x * blockDim.x;
    for (; i < E; i += stride) {
        int s = edge_at(e, e64, is64, i);
        int d = edge_at(e, e64, is64, (long long)E + i);
        int pos = atomicAdd(&cursor[d], 1);
        ew[pos] = make_int2(s, __float_as_int(dinv[s] * dinv[d]));
    }
}

// ---------------- W prepack into MFMA B-fragment layout (raw bf16) ----------------
__global__ void k_prepack(const float* __restrict__ W1, const float* __restrict__ W2,
                          const float* __restrict__ W3, const float* __restrict__ Wl,
                          unsigned short* __restrict__ bp) {
    int job = blockIdx.x;
    const float* src;
    int rowoff = 0;
    if (job == 0) src = W1;
    else if (job == 1) src = W2;
    else if (job == 2) src = W3;
    else { src = Wl; rowoff = (job - 3) * 128; }
    unsigned short* dst = bp + job * 16384;
    for (int idx = threadIdx.x; idx < 16384; idx += 256) {
        int j = idx & 7, l = (idx >> 3) & 63, kt = (idx >> 9) & 3, nt = idx >> 11;
        int row = kt * 32 + (l >> 4) * 8 + j;
        int col = nt * 16 + (l & 15);
        dst[idx] = f2b(src[(rowoff + row) * 128 + col]);
    }
}

// ---------------- layer GEMM: zb = A @ Bp(+c), B staged in LDS, one tile/wave ----------------
template <int HAS_C, int A32>
__global__ __launch_bounds__(256) void k_gemm_z(const void* __restrict__ Av,
                                                const unsigned short* __restrict__ Bp,
                                                const float* __restrict__ cvec,
                                                unsigned short* __restrict__ zb, int n) {
    __shared__ short8 sB[2048];  // 32 KB
    int tid = threadIdx.x;
    {
        const short8* bp8 = (const short8*)Bp;
        for (int i = tid; i < 2048; i += 256) sB[i] = bp8[i];
    }
    __syncthreads();
    int l = tid & 63, w = tid >> 6;
    int kgrp = l >> 4, rit = l & 15;
    int tile = blockIdx.x * 4 + w;
    int ntile = n >> 4;
    if (tile >= ntile) return;
    int r0 = tile * 16;
    short8 afs[4];
    if (A32) {
        const float* a32 = (const float*)Av + (size_t)(r0 + rit) * 128 + kgrp * 8;
#pragma unroll
        for (int kt = 0; kt < 4; ++kt) {
            float4 fa = *(const float4*)(a32 + kt * 32);
            float4 fb = *(const float4*)(a32 + kt * 32 + 4);
            short8 af;
            af[0] = (short)f2b(fa.x); af[1] = (short)f2b(fa.y);
            af[2] = (short)f2b(fa.z); af[3] = (short)f2b(fa.w);
            af[4] = (short)f2b(fb.x); af[5] = (short)f2b(fb.y);
            af[6] = (short)f2b(fb.z); af[7] = (short)f2b(fb.w);
            afs[kt] = af;
        }
    } else {
        const unsigned short* a16 = (const unsigned short*)Av + (size_t)(r0 + rit) * 128 + kgrp * 8;
#pragma unroll
        for (int kt = 0; kt < 4; ++kt) afs[kt] = *(const short8*)(a16 + kt * 32);
    }
    f32x4 acc[8];
#pragma unroll
    for (int nt = 0; nt < 8; ++nt) acc[nt] = (f32x4)(0.f);
#pragma unroll
    for (int kt = 0; kt < 4; ++kt)
#pragma unroll
        for (int nt = 0; nt < 8; ++nt)
            acc[nt] = __builtin_amdgcn_mfma_f32_16x16x32_bf16(afs[kt], sB[(nt * 4 + kt) * 64 + l], acc[nt], 0, 0, 0);
    int crow0 = kgrp * 4, ccol = l & 15;
#pragma unroll
    for (int nt = 0; nt < 8; ++nt) {
        int col = nt * 16 + ccol;
        float cv = HAS_C ? cvec[col] : 0.f;
#pragma unroll
        for (int j = 0; j < 4; ++j)
            zb[(size_t)(r0 + crow0 + j) * 128 + col] = f2b(acc[nt][j] + cv);
    }
}

// ---------------- CSR-pull aggregate + relu + BN stats (one node per wave) ----------------
__global__ __launch_bounds__(256) void k_agg(const unsigned short* __restrict__ zb,
                                             const int* __restrict__ row_ptr,
                                             const int2* __restrict__ ew,
                                             const float* __restrict__ dinv,
                                             const float* __restrict__ bias,
                                             unsigned int* __restrict__ tb,
                                             float* __restrict__ stats64, int n) {
    int tid = threadIdx.x;
    int l = tid & 63, w = tid >> 6;
    int node = blockIdx.x * 4 + w;  // grid is exactly n/4 blocks
    const unsigned int* z32 = (const unsigned int*)zb;
    float b0 = bias[2 * l], b1 = bias[2 * l + 1];
    float di = dinv[node];
    unsigned int us = z32[((size_t)node << 6) | l];
    float di2 = di * di;
    float acc0 = fmaf(di2, b2f_lo(us), b0);
    float acc1 = fmaf(di2, b2f_hi(us), b1);
    int e0 = row_ptr[node], e1 = row_ptr[node + 1];
    int last = max(e1 - 1, 0);
    int2 q[8];
#pragma unroll
    for (int j = 0; j < 8; ++j) {
        int idx = e0 + j;
        int2 t = ew[min(idx, last)];
        q[j] = make_int2(t.x, idx < e1 ? t.y : 0);
    }
    int iters = (e1 - e0 + 7) >> 3;
    for (int it = 0; it < iters; ++it) {
        unsigned int u[8];
        float wf[8];
#pragma unroll
        for (int j = 0; j < 8; ++j) {
            u[j] = z32[(size_t)(unsigned int)((q[j].x << 6) | l)];
            wf[j] = __int_as_float(q[j].y);
        }
        int eb = e0 + (it + 1) * 8;
#pragma unroll
        for (int j = 0; j < 8; ++j) {
            int idx = eb + j;
            int2 t = ew[min(idx, last)];
            q[j] = make_int2(t.x, idx < e1 ? t.y : 0);
        }
#pragma unroll
        for (int j = 0; j < 8; ++j) {
            acc0 = fmaf(wf[j], b2f_lo(u[j]), acc0);
            acc1 = fmaf(wf[j], b2f_hi(u[j]), acc1);
        }
    }
    acc0 = fmaxf(acc0, 0.f);
    acc1 = fmaxf(acc1, 0.f);
    tb[((size_t)node << 6) | l] = pack2(acc0, acc1);
    __shared__ float red[4][256];
    red[0][tid] = acc0; red[1][tid] = acc1;
    red[2][tid] = acc0 * acc0; red[3][tid] = acc1 * acc1;
    __syncthreads();
    int k = tid >> 6, li = tid & 63;
    float v = red[k][li] + red[k][64 + li] + red[k][128 + li] + red[k][192 + li];
    int f = 2 * li + (k & 1) + ((k >> 1) ? 128 : 0);
    atomicAdd(&stats64[(blockIdx.x & 63) * 256 + f], v);
}

// ---------------- fused BN finalize + shift-dots + B pre-scale ----------------
// grid 2 always. Per layer: stats -> (sc, sh); cn = sh@Wn (modes 0,1);
// cl = base+sh@Wl (0) or cl += sh@Wl (1,2); scale next-layer prepacked W (modes 0,1)
// and this layer's Wl block into bf16 (folds BN scale out of the GEMMs).
template <int MODE>
__global__ void k_bn_findots(const float* __restrict__ stats64,
                             const float* __restrict__ g, const float* __restrict__ be,
                             float invn, float* __restrict__ ss_out,
                             const float* __restrict__ Wn, float* __restrict__ cn,
                             const float* __restrict__ Wl, const float* __restrict__ base,
                             float* __restrict__ cl,
                             const unsigned short* __restrict__ bpn_src,
                             unsigned short* __restrict__ bpn_dst,
                             const unsigned short* __restrict__ bpl_src,
                             unsigned short* __restrict__ bpl_dst) {
    int tid = threadIdx.x;  // 256
    float a = 0.f;
#pragma unroll 8
    for (int c = 0; c < 64; ++c) a += stats64[c * 256 + tid];
    __shared__ float sums[256];
    __shared__ float sh[128];
    __shared__ float scs[128];
    sums[tid] = a;
    __syncthreads();
    if (tid < 128) {
        float m = sums[tid] * invn;
        float var = sums[128 + tid] * invn - m * m;
        float sc = g[tid] * rsqrtf(var + BN_EPS);
        scs[tid] = sc;
        sh[tid] = fmaf(-m, sc, be[tid]);
    }
    __syncthreads();
    if (blockIdx.x == 0 && tid < 128) {
        ss_out[tid] = scs[tid];
        ss_out[128 + tid] = sh[tid];
    }
    bool doCl = (MODE == 2) ? (blockIdx.x == 0) : (blockIdx.x == 1);
    bool doCn = (MODE < 2) && (blockIdx.x == 0);
    if (doCl || doCn) {
        const float* W = doCl ? Wl : Wn;
        int col = tid & 127, half = tid >> 7;
        float acc = 0.f;
#pragma unroll 4
        for (int k = half * 64; k < half * 64 + 64; ++k) acc = fmaf(sh[k], W[k * 128 + col], acc);
        __syncthreads();
        sums[tid] = acc;
        __syncthreads();
        if (tid < 128) {
            float tot = sums[tid] + sums[128 + tid];
            if (doCl) cl[tid] = ((MODE == 0) ? base[tid] : cl[tid]) + tot;
            else cn[tid] = tot;
        }
    }
    // scale prepacked B fragments by per-k scs
    int beg = blockIdx.x * 8192;
    if (MODE < 2) {
        for (int idx = beg + tid; idx < beg + 8192; idx += 256) {
            int k = ((idx >> 9) & 3) * 32 + ((idx >> 7) & 3) * 8 + (idx & 7);
            bpn_dst[idx] = f2b(us2f(bpn_src[idx]) * scs[k]);
        }
    }
    for (int idx = beg + tid; idx < beg + 8192; idx += 256) {
        int k = ((idx >> 9) & 3) * 32 + ((idx >> 7) & 3) * 8 + (idx & 7);
        bpl_dst[idx] = f2b(us2f(bpl_src[idx]) * scs[k]);
    }
}

// ---------------- final GEMM: out = relu([t1|t2|t3] @ BpL + cl), fp32 ----------------
// K-block 0 from LDS (32 KB); K-blocks 1,2 in per-wave registers (prescaled).
__global__ __launch_bounds__(256) void k_gemm_final(const unsigned short* __restrict__ t1,
                                                    const unsigned short* __restrict__ t2,
                                                    const unsigned short* __restrict__ t3,
                                                    const unsigned short* __restrict__ Bp,
                                                    const float* __restrict__ cl,
                                                    float* __restrict__ out, int n) {
    __shared__ short8 sB[2048];  // 32 KB: K-block 0
    int tid = threadIdx.x;
    const short8* bp8 = (const short8*)Bp;
    for (int i = tid; i < 2048; i += 256) sB[i] = bp8[i];
    int l = tid & 63, w = tid >> 6;
    int kgrp = l >> 4, rit = l & 15;
    short8 breg[2][8];
#pragma unroll
    for (int b = 1; b < 3; ++b)
#pragma unroll
        for (int i = 0; i < 2; ++i)
#pragma unroll
            for (int kt = 0; kt < 4; ++kt)
                breg[i][(b - 1) * 4 + kt] = bp8[b * 2048 + ((2 * w + i) * 4 + kt) * 64 + l];
    __syncthreads();
    int ntile = n >> 4;
    int ccol = l & 15;
    int col0 = 2 * w * 16 + ccol, col1 = col0 + 16;
    float cv0 = cl[col0], cv1 = cl[col1];
    for (int tile = blockIdx.x; tile < ntile; tile += gridDim.x) {
        int r0 = tile * 16;
        size_t abase = (size_t)(r0 + rit) * 128 + kgrp * 8;
        short8 af[12];
#pragma unroll
        for (int kt = 0; kt < 4; ++kt) {
            af[kt]     = *(const short8*)(t1 + abase + kt * 32);
            af[4 + kt] = *(const short8*)(t2 + abase + kt * 32);
            af[8 + kt] = *(const short8*)(t3 + abase + kt * 32);
        }
        f32x4 acc0 = (f32x4)(0.f), acc1 = (f32x4)(0.f);
#pragma unroll
        for (int kt = 0; kt < 4; ++kt) {
            acc0 = __builtin_amdgcn_mfma_f32_16x16x32_bf16(af[kt], sB[((2 * w) * 4 + kt) * 64 + l], acc0, 0, 0, 0);
            acc1 = __builtin_amdgcn_mfma_f32_16x16x32_bf16(af[kt], sB[((2 * w + 1) * 4 + kt) * 64 + l], acc1, 0, 0, 0);
        }
#pragma unroll
        for (int kt = 0; kt < 4; ++kt) {
            acc0 = __builtin_amdgcn_mfma_f32_16x16x32_bf16(af[4 + kt], breg[0][kt], acc0, 0, 0, 0);
            acc1 = __builtin_amdgcn_mfma_f32_16x16x32_bf16(af[4 + kt], breg[1][kt], acc1, 0, 0, 0);
        }
#pragma unroll
        for (int kt = 0; kt < 4; ++kt) {
            acc0 = __builtin_amdgcn_mfma_f32_16x16x32_bf16(af[8 + kt], breg[0][4 + kt], acc0, 0, 0, 0);
            acc1 = __builtin_amdgcn_mfma_f32_16x16x32_bf16(af[8 + kt], breg[1][4 + kt], acc1, 0, 0, 0);
        }
        int crow0 = kgrp * 4;
#pragma unroll
        for (int j = 0; j < 4; ++j) {
            int row = r0 + crow0 + j;
            out[(size_t)row * 128 + col0] = fmaxf(acc0[j] + cv0, 0.f);
            out[(size_t)row * 128 + col1] = fmaxf(acc1[j] + cv1, 0.f);
        }
    }
}

extern "C" void kernel_launch(void* const* d_in, const int* in_sizes, int n_in,
                              void* d_out, int out_size, void* d_ws, size_t ws_size,
                              hipStream_t stream) {
    const float* x   = (const float*)d_in[0];
    const int*   ei  = (const int*)d_in[1];
    const float* W1  = (const float*)d_in[3];
    const float* b1  = (const float*)d_in[4];
    const float* g1  = (const float*)d_in[5];
    const float* be1 = (const float*)d_in[6];
    const float* W2  = (const float*)d_in[7];
    const float* b2  = (const float*)d_in[8];
    const float* g2  = (const float*)d_in[9];
    const float* be2 = (const float*)d_in[10];
    const float* W3  = (const float*)d_in[11];
    const float* b3  = (const float*)d_in[12];
    const float* g3  = (const float*)d_in[13];
    const float* be3 = (const float*)d_in[14];
    const float* Wl  = (const float*)d_in[15];
    const float* bl  = (const float*)d_in[16];
    float* out = (float*)d_out;

    const int n = N_NODES;
    const int E = in_sizes[1] / 2;

    char* ws = (char*)d_ws;
    size_t off = 0;
    auto alloc = [&](size_t bytes) -> void* {
        void* p = ws + off;
        off += (bytes + 255) & ~((size_t)255);
        return p;
    };
    // zero-region: cnt + 3 striped stats buffers, contiguous, one memset
    int*            cnt     = (int*)alloc((size_t)n * 4);
    float*          st1     = (float*)alloc(64 * 256 * 4);
    float*          st2     = (float*)alloc(64 * 256 * 4);
    float*          st3     = (float*)alloc(64 * 256 * 4);
    size_t zero_bytes = (size_t)((char*)st3 + 64 * 256 * 4 - (char*)cnt);

    float*          dinv    = (float*)alloc((size_t)n * 4);
    int*            row_ptr = (int*)alloc((size_t)(n + 1) * 4);
    int*            cursor  = (int*)alloc((size_t)n * 4);
    int*            bsum    = (int*)alloc(64 * 4);
    int*            boff    = (int*)alloc(64 * 4);
    float*          ss1     = (float*)alloc(256 * 4);
    float*          ss2     = (float*)alloc(256 * 4);
    float*          ss3     = (float*)alloc(256 * 4);
    float*          c2      = (float*)alloc(128 * 4);
    float*          c3      = (float*)alloc(128 * 4);
    float*          cl      = (float*)alloc(128 * 4);
    int*            flag    = (int*)alloc(256);
    int2*           ew      = (int2*)alloc((size_t)E * 8);
    unsigned short* bp      = (unsigned short*)alloc(6 * 16384 * 2);   // raw prepack
    unsigned short* bpsN    = (unsigned short*)alloc(16384 * 2);       // scaled next-layer W
    unsigned short* bpsL    = (unsigned short*)alloc(3 * 16384 * 2);   // scaled Wl blocks
    unsigned short* zb      = (unsigned short*)alloc((size_t)n * 128 * 2);
    unsigned int*   tb1     = (unsigned int*)alloc((size_t)n * 64 * 4);
    unsigned int*   tb2     = (unsigned int*)alloc((size_t)n * 64 * 4);
    unsigned int*   tb3     = (unsigned int*)alloc((size_t)n * 64 * 4);

    hipMemsetAsync(cnt, 0, zero_bytes, stream);

    // ---- CSR build ----
    k_detect64<<<1, 256, 0, stream>>>(ei, flag);
    k_deg_count<<<512, 256, 0, stream>>>(ei, flag, cnt, E);
    k_dinv<<<(n + 255) / 256, 256, 0, stream>>>(cnt, dinv, n);
    int nchunks = (n + SCAN_CHUNK - 1) / SCAN_CHUNK;
    k_chunk_sum<<<nchunks, 256, 0, stream>>>(cnt, bsum, n);
    k_scan_sums<<<1, 32, 0, stream>>>(bsum, boff, row_ptr, nchunks, n);
    k_local_scan<<<nchunks, 256, 0, stream>>>(cnt, boff, row_ptr, cursor, n);
    k_fill<<<512, 256, 0, stream>>>(ei, flag, dinv, cursor, ew, E);

    k_prepack<<<6, 256, 0, stream>>>(W1, W2, W3, Wl, bp);

    const unsigned short* t1u = (const unsigned short*)tb1;
    const unsigned short* t2u = (const unsigned short*)tb2;
    const unsigned short* t3u = (const unsigned short*)tb3;
    float invn = 1.0f / n;
    int aggblk = n / 4;    // one node per wave
    int gemmblk = 782;     // ceil(3125 tiles / 4 waves)

    // ---- layer 1 (reads x fp32 directly; raw W1) ----
    k_gemm_z<0, 1><<<gemmblk, 256, 0, stream>>>(x, bp, nullptr, zb, n);
    k_agg<<<aggblk, 256, 0, stream>>>(zb, row_ptr, ew, dinv, b1, tb1, st1, n);
    k_bn_findots<0><<<2, 256, 0, stream>>>(st1, g1, be1, invn, ss1, W2, c2, Wl, bl, cl,
                                           bp + 16384, bpsN, bp + 3 * 16384, bpsL);

    // ---- layer 2 (prescaled W2) ----
    k_gemm_z<1, 0><<<gemmblk, 256, 0, stream>>>(t1u, bpsN, c2, zb, n);
    k_agg<<<aggblk, 256, 0, stream>>>(zb, row_ptr, ew, dinv, b2, tb2, st2, n);
    k_bn_findots<1><<<2, 256, 0, stream>>>(st2, g2, be2, invn, ss2, W3, c3, Wl + 16384, nullptr, cl,
                                           bp + 2 * 16384, bpsN, bp + 4 * 16384, bpsL + 16384);

    // ---- layer 3 (prescaled W3) ----
    k_gemm_z<1, 0><<<gemmblk, 256, 0, stream>>>(t2u, bpsN, c3, zb, n);
    k_agg<<<aggblk, 256, 0, stream>>>(zb, row_ptr, ew, dinv, b3, tb3, st3, n);
    k_bn_findots<2><<<2, 256, 0, stream>>>(st3, g3, be3, invn, ss3, nullptr, nullptr,
                                           Wl + 2 * 16384, nullptr, cl,
                                           nullptr, nullptr, bp + 5 * 16384, bpsL + 2 * 16384);

    // ---- final fused GEMM over K=384 (prescaled Wl) ----
    k_gemm_final<<<512, 256, 0, stream>>>(t1u, t2u, t3u, bpsL, cl, out, n);
}